// Round 2
// baseline (1455.269 us; speedup 1.0000x reference)
//
#include <hip/hip_runtime.h>
#include <hip/hip_bf16.h>
#include <math.h>
#include <stdint.h>

// Problem constants (from setup_inputs)
#define B_ 32
#define T_ 512
#define D_ 1024
#define N_ 50000
#define S_ 4096

// 1 / log(N+1) = 1 / log(50001)
#define INV_LOG_NP1 0.09242317f

// W is pre-scaled by 64 when converting to fp8 e4m3 (raw W*0.02 lands in the
// subnormal zone); the GEMM accumulator is multiplied by 1/64 in the epilogue.
#define WSCALE 64.0f
#define INV_WSCALE 0.015625f
#define LOG2E 1.4426950408889634f

// e8m0 scale = 127 -> 2^0 = 1.0 in every byte (opsel-proof)
#define SCALE_ONE 0x7F7F7F7F

typedef __attribute__((ext_vector_type(8))) short bf16x8;   // bf16 MFMA A/B frag
typedef __attribute__((ext_vector_type(4))) float f32x4;    // MFMA C/D frag
typedef __attribute__((ext_vector_type(4))) short s16x4;    // 8B store
typedef __attribute__((ext_vector_type(8))) int i32x8;      // MX MFMA A/B frag (32B)

// fp32 -> bf16 round-to-nearest-even (fallback path)
__device__ __forceinline__ short f2bf(float f) {
    unsigned u = __float_as_uint(f);
    u += 0x7fffu + ((u >> 16) & 1u);
    return (short)(u >> 16);
}

// pack 4 floats -> 4 fp8 e4m3 bytes (HW cvt, OCP format on gfx950)
__device__ __forceinline__ int pack_fp8x4(float a, float b, float c, float d) {
    int v = __builtin_amdgcn_cvt_pk_fp8_f32(a, b, 0, false);   // bytes 0,1
    v = __builtin_amdgcn_cvt_pk_fp8_f32(c, d, v, true);        // bytes 2,3
    return v;
}

// log E[count] for log-uniform unique sampling (TF formula), fp32 like the ref
__device__ __forceinline__ float log_expected(int id) {
    float p  = log1pf(1.0f / ((float)id + 1.0f)) * INV_LOG_NP1;  // P(c)
    return logf(-expm1f((float)S_ * log1pf(-p)));                // log(1-(1-p)^S)
}

// async global->LDS, 16 B per lane; LDS dest = wave-uniform base + lane*16
__device__ __forceinline__ void gload_lds16(const void* g, void* l) {
    __builtin_amdgcn_global_load_lds(
        (const __attribute__((address_space(1))) void*)g,
        (__attribute__((address_space(3))) void*)l, 16, 0, 0);
}

// ---------------------------------------------------------------------------
// Kernel P (fast path): fused {W fp32 -> fp8 table} + {true logits + x -> fp8}.
// Blocks [0, NCVT) convert W (each thread 8 elems, exactly covers N*D).
// Blocks [NCVT, NCVT + B*T/4) compute true logits, one wave per token, and
// emit x in fp8 (x is being read here anyway).
__global__ __launch_bounds__(256) void prep_kernel(
    const float* __restrict__ x, const float* __restrict__ W,
    const float* __restrict__ bvec, const int* __restrict__ labels,
    float* __restrict__ true_logit, float* __restrict__ denom,
    unsigned char* __restrict__ xf8, unsigned char* __restrict__ Wf8)
{
    constexpr int NCVT = N_ * D_ / 2048;        // 25000
    if (blockIdx.x < NCVT) {
        size_t i = ((size_t)blockIdx.x * 2048) + (size_t)threadIdx.x * 8;
        float4 a = *(const float4*)(W + i);
        float4 b = *(const float4*)(W + i + 4);
        int2 o;
        o.x = pack_fp8x4(a.x * WSCALE, a.y * WSCALE, a.z * WSCALE, a.w * WSCALE);
        o.y = pack_fp8x4(b.x * WSCALE, b.y * WSCALE, b.z * WSCALE, b.w * WSCALE);
        *(int2*)(Wf8 + i) = o;
        return;
    }
    int w = threadIdx.x >> 6, lane = threadIdx.x & 63;
    int token = (blockIdx.x - NCVT) * 4 + w;    // B*T/4 blocks, exact
    int lab = labels[token];
    const float4* xp = (const float4*)(x + (size_t)token * D_);
    const float4* wp = (const float4*)(W + (size_t)lab * D_);
    float acc = 0.0f;
#pragma unroll
    for (int j = 0; j < 4; ++j) {               // 1024 floats = 256 float4 / 64 lanes
        float4 a = xp[lane + 64 * j];
        float4 c = wp[lane + 64 * j];
        acc += a.x * c.x + a.y * c.y + a.z * c.z + a.w * c.w;
        int o = pack_fp8x4(a.x, a.y, a.z, a.w);
        *(int*)(xf8 + (size_t)token * D_ + (lane + 64 * j) * 4) = o;
    }
#pragma unroll
    for (int m = 32; m >= 1; m >>= 1) acc += __shfl_xor(acc, m);
    if (lane == 0) {
        float tl = acc + bvec[lab] - log_expected(lab);
        true_logit[token] = tl;
        denom[token] = __expf(tl);
    }
}

// ---------------------------------------------------------------------------
// Kernel 1 (FALLBACK): true logits only (no fp8 emit).
__global__ __launch_bounds__(256) void true_logit_kernel(
    const float* __restrict__ x, const float* __restrict__ W,
    const float* __restrict__ bvec, const int* __restrict__ labels,
    float* __restrict__ true_logit, float* __restrict__ denom)
{
    int w = threadIdx.x >> 6, lane = threadIdx.x & 63;
    int token = blockIdx.x * 4 + w;             // grid = B*T/4, exact
    int lab = labels[token];
    const float4* xp = (const float4*)(x + (size_t)token * D_);
    const float4* wp = (const float4*)(W + (size_t)lab * D_);
    float acc = 0.0f;
#pragma unroll
    for (int j = 0; j < 4; ++j) {
        float4 a = xp[lane + 64 * j];
        float4 c = wp[lane + 64 * j];
        acc += a.x * c.x + a.y * c.y + a.z * c.z + a.w * c.w;
    }
#pragma unroll
    for (int m = 32; m >= 1; m >>= 1) acc += __shfl_xor(acc, m);
    if (lane == 0) {
        float tl = acc + bvec[lab] - log_expected(lab);
        true_logit[token] = tl;
        denom[token] = __expf(tl);
    }
}

constexpr int BM = 128, BN = 128;

// ---------------------------------------------------------------------------
// Kernel 2 (FAST): fused sampled-logits GEMM + exp-sum epilogue, fp8 e4m3 via
// the block-scaled MX pipe (mfma_scale 16x16x128, unit e8m0 scales), single-
// buffered (m97-style) global_load_lds(16B) staging, BK=128 (bytes).
//
// K-PERMUTATION TRICK: result invariant under any K-permutation applied to
// both A and B.  Lane quad lq (=lane>>4) consumes global k = lq*32..lq*32+31:
// exactly the two staged 16-B chunks (2lq, 2lq+1) -> one K=128 MX fragment
// (32 B/lane), conflict-free ds_read_b128 x2.  A and B use the identical
// (lane,byte)->k mapping, so the HW's internal k ordering cannot break
// correctness.  Unit scales (0x7F) keep products bit-identical to the
// non-scaled fp8 path (round-1 verified: passed).
//
// LDS layout: row = 128 B = 8 chunks of 16 B; chunk c of row r at slot c^(r&7).
// Staging: lane l loads chunk (l&7)^(l>>3) of row seg*8+(l>>3).
//
// REGISTER DISCIPLINE (round-1 post-mortem: 256 VGPR + scratch spill at 1
// block/CU): load the 4 B fragments once (32 VGPR), stream A one fragment at
// a time (8 VGPR) through its 4 MFMAs; ds_read lands directly in the operand
// vector halves.  __launch_bounds__(256,3) caps regs ~170 -> 3 blocks/CU,
// restoring the multi-block overlap the m97 structure needs.
__global__ __launch_bounds__(256, 3) void sampled_gemm_fp8(
    const unsigned char* __restrict__ xf8, const unsigned char* __restrict__ Wf8,
    const float* __restrict__ bvec, const int* __restrict__ labels,
    const int* __restrict__ sampled, float* __restrict__ denom)
{
    constexpr int BK = 128;           // K-bytes (= K elems, fp8)
    __shared__ __align__(16) unsigned char At[BM * BK];   // 16 KB
    __shared__ __align__(16) unsigned char Bt[BN * BK];   // 16 KB
    __shared__ float colbias[BN];     // (b - logE) * log2(e)
    __shared__ int   ids[BN];
    __shared__ int   labT[BM];

    int bidx = blockIdx.x;            // grid = B * (T/BM) * (S/BN) = 32*4*32
    int b    = bidx >> 7;
    int rem  = bidx & 127;
    int mT   = rem >> 5;
    int nT   = rem & 31;

    int tid  = threadIdx.x;
    int w    = tid >> 6, lane = tid & 63;

    // ---- staging geometry: 1 KB per issue = 8 rows x 128 B ----
    int r = lane >> 3;                       // 0..7 row within 8-row segment
    int s = lane & 7;                        // LDS slot (16 B units)
    int c = s ^ r;                           // global chunk this lane loads

    int tokBase = b * T_ + mT * BM;
    const unsigned char* gA[4];
    const unsigned char* gB[4];
    unsigned char* lA[4];
    unsigned char* lB[4];
#pragma unroll
    for (int j = 0; j < 4; ++j) {
        int seg = 4 * w + j;                 // wave w stages segments 4w..4w+3
        int row = seg * 8 + r;               // 0..127
        gA[j] = xf8 + (size_t)(tokBase + row) * D_ + c * 16;
        int id = sampled[b * S_ + nT * BN + row];
        gB[j] = Wf8 + (size_t)id * D_ + c * 16;
        lA[j] = At + seg * 1024;             // 1 KB per segment
        lB[j] = Bt + seg * 1024;
    }

#define STAGE()                                                      \
    do {                                                             \
        _Pragma("unroll")                                            \
        for (int j = 0; j < 4; ++j) { gload_lds16(gA[j], lA[j]); gA[j] += BK; } \
        _Pragma("unroll")                                            \
        for (int j = 0; j < 4; ++j) { gload_lds16(gB[j], lB[j]); gB[j] += BK; } \
    } while (0)

    // Issue first tile ASAP; prologue transcendentals overlap the loads.
    STAGE();

    // ---- prologue: epilogue metadata into LDS ----
    if (tid < BN) {
        int id = sampled[b * S_ + nT * BN + tid];
        ids[tid] = id;
        colbias[tid] = (bvec[id] - log_expected(id)) * LOG2E;
    } else {
        int i = tid - BN;
        labT[i] = labels[b * T_ + mT * BM + i];
    }

    f32x4 acc[4][4];
#pragma unroll
    for (int mi = 0; mi < 4; ++mi)
#pragma unroll
        for (int ni = 0; ni < 4; ++ni) acc[mi][ni] = (f32x4){0.f, 0.f, 0.f, 0.f};

    int waveM = w >> 1, waveN = w & 1;
    int lr = lane & 15, lq = lane >> 4;
    // Fragment row byte-bases and per-chunk swizzled offsets
    int aRow[4], bRow[4];
#pragma unroll
    for (int i = 0; i < 4; ++i) {
        aRow[i] = (waveM * 64 + i * 16 + lr) * BK;
        bRow[i] = (waveN * 64 + i * 16 + lr) * BK;
    }
    int offP[2];
#pragma unroll
    for (int tp = 0; tp < 2; ++tp)
        offP[tp] = ((2 * lq + tp) ^ (lr & 7)) * 16;

    for (int k0 = 0; k0 < D_; k0 += BK) {
        if (k0) {
            __syncthreads();                  // LDS consumers of prev tile done
            STAGE();
        }
        __syncthreads();                      // drain staging (vmcnt(0))

        // B fragments: loaded once, reused by all 4 A fragments (32 VGPR).
        i32x8 bv[4];
#pragma unroll
        for (int ni = 0; ni < 4; ++ni) {
            int4* h = (int4*)&bv[ni];
            h[0] = *(const int4*)(Bt + bRow[ni] + offP[0]);
            h[1] = *(const int4*)(Bt + bRow[ni] + offP[1]);
        }
        // A fragments streamed one at a time (8 VGPR live).
#pragma unroll
        for (int mi = 0; mi < 4; ++mi) {
            i32x8 a;
            int4* h = (int4*)&a;
            h[0] = *(const int4*)(At + aRow[mi] + offP[0]);
            h[1] = *(const int4*)(At + aRow[mi] + offP[1]);
#pragma unroll
            for (int ni = 0; ni < 4; ++ni)
                acc[mi][ni] = __builtin_amdgcn_mfma_scale_f32_16x16x128_f8f6f4(
                    a, bv[ni], acc[mi][ni],
                    0, 0,                      // cbsz/blgp: fp8 e4m3 both
                    0, SCALE_ONE,              // opsel_a, scale_a = 1.0
                    0, SCALE_ONE);             // opsel_b, scale_b = 1.0
        }
    }
#undef STAGE

    // Epilogue: exp2-domain (acc and bias pre-scaled by log2e), accidental-hit
    // mask, row-sum, atomicAdd.
    // C/D layout (shape-determined, verified m89/m91/m127):
    // col = lane&15, row = (lane>>4)*4 + reg
    const float accScale = INV_WSCALE * LOG2E;
    float* dptr = denom + b * T_ + mT * BM;
#pragma unroll
    for (int mi = 0; mi < 4; ++mi) {
#pragma unroll
        for (int rr = 0; rr < 4; ++rr) {
            int localRow = waveM * 64 + mi * 16 + lq * 4 + rr;
            int lab = labT[localRow];
            float sum = 0.0f;
#pragma unroll
            for (int ni = 0; ni < 4; ++ni) {
                int col = waveN * 64 + ni * 16 + lr;
                float v = acc[mi][ni][rr] * accScale + colbias[col];
                sum += (ids[col] == lab) ? 0.0f : exp2f(v);
            }
            sum += __shfl_xor(sum, 1);
            sum += __shfl_xor(sum, 2);
            sum += __shfl_xor(sum, 4);
            sum += __shfl_xor(sum, 8);
            if (lr == 0) atomicAdd(&dptr[localRow], sum);
        }
    }
}

// ---------------------------------------------------------------------------
// Kernel 2 (FALLBACK): register-staging fp32->bf16 GEMM (small-ws path).
__global__ __launch_bounds__(256) void sampled_gemm(
    const float* __restrict__ x, const float* __restrict__ W,
    const float* __restrict__ bvec, const int* __restrict__ labels,
    const int* __restrict__ sampled, float* __restrict__ denom)
{
    constexpr int FBK = 32;
    __shared__ short At[BM * FBK];
    __shared__ short Bt[BN * FBK];
    __shared__ float colbias[BN];
    __shared__ int   ids[BN];
    __shared__ int   labT[BM];

    int bidx = blockIdx.x;
    int b    = bidx >> 7;
    int rem  = bidx & 127;
    int mT   = rem >> 5;
    int nT   = rem & 31;
    int tid = threadIdx.x;

    if (tid < BN) {
        int id = sampled[b * S_ + nT * BN + tid];
        ids[tid] = id;
        colbias[tid] = bvec[id] - log_expected(id);
    } else {
        int i = tid - BN;
        labT[i] = labels[b * T_ + mT * BM + i];
    }
    __syncthreads();

    const float* asrc[4];
    const float* bsrc[4];
    int ch = tid & 7;
#pragma unroll
    for (int j = 0; j < 4; ++j) {
        int row = (tid >> 3) + 32 * j;
        asrc[j] = x + ((size_t)(b * T_ + mT * BM + row)) * D_ + ch * 4;
        bsrc[j] = W + (size_t)ids[row] * D_ + ch * 4;
    }

    f32x4 acc[4][4];
#pragma unroll
    for (int mi = 0; mi < 4; ++mi)
#pragma unroll
        for (int ni = 0; ni < 4; ++ni) acc[mi][ni] = (f32x4){0.f, 0.f, 0.f, 0.f};

    int w = tid >> 6, lane = tid & 63;
    int waveM = w >> 1, waveN = w & 1;
    int lr = lane & 15, lq = lane >> 4;

    for (int k0 = 0; k0 < D_; k0 += FBK) {
        __syncthreads();
#pragma unroll
        for (int j = 0; j < 4; ++j) {
            int row = (tid >> 3) + 32 * j;
            float4 va = *(const float4*)(asrc[j] + k0);
            s16x4 pa = {f2bf(va.x), f2bf(va.y), f2bf(va.z), f2bf(va.w)};
            *(s16x4*)&At[row * FBK + ch * 4] = pa;
            float4 vb = *(const float4*)(bsrc[j] + k0);
            s16x4 pb = {f2bf(vb.x), f2bf(vb.y), f2bf(vb.z), f2bf(vb.w)};
            *(s16x4*)&Bt[row * FBK + ch * 4] = pb;
        }
        __syncthreads();
        bf16x8 af[4], bfr[4];
#pragma unroll
        for (int mi = 0; mi < 4; ++mi)
            af[mi] = *(const bf16x8*)&At[(waveM * 64 + mi * 16 + lr) * FBK + lq * 8];
#pragma unroll
        for (int ni = 0; ni < 4; ++ni)
            bfr[ni] = *(const bf16x8*)&Bt[(waveN * 64 + ni * 16 + lr) * FBK + lq * 8];
#pragma unroll
        for (int mi = 0; mi < 4; ++mi)
#pragma unroll
            for (int ni = 0; ni < 4; ++ni)
                acc[mi][ni] = __builtin_amdgcn_mfma_f32_16x16x32_bf16(
                    af[mi], bfr[ni], acc[mi][ni], 0, 0, 0);
    }

    float* dptr = denom + b * T_ + mT * BM;
#pragma unroll
    for (int mi = 0; mi < 4; ++mi) {
#pragma unroll
        for (int rr = 0; rr < 4; ++rr) {
            int localRow = waveM * 64 + mi * 16 + lq * 4 + rr;
            int lab = labT[localRow];
            float sum = 0.0f;
#pragma unroll
            for (int ni = 0; ni < 4; ++ni) {
                int col = waveN * 64 + ni * 16 + lr;
                float v = acc[mi][ni][rr] + colbias[col];
                sum += (ids[col] == lab) ? 0.0f : __expf(v);
            }
            sum += __shfl_xor(sum, 1);
            sum += __shfl_xor(sum, 2);
            sum += __shfl_xor(sum, 4);
            sum += __shfl_xor(sum, 8);
            if (lr == 0) atomicAdd(&dptr[localRow], sum);
        }
    }
}

// ---------------------------------------------------------------------------
// Kernel 3: token_loss = log(denom) - true_logit; out = 0.5 * mean
__global__ __launch_bounds__(256) void finalize_kernel(
    const float* __restrict__ true_logit, const float* __restrict__ denom,
    float* __restrict__ out)
{
    float s = 0.0f;
    for (int i = threadIdx.x; i < B_ * T_; i += 256)
        s += __logf(denom[i]) - true_logit[i];
#pragma unroll
    for (int m = 32; m >= 1; m >>= 1) s += __shfl_xor(s, m);
    __shared__ float wsum[4];
    if ((threadIdx.x & 63) == 0) wsum[threadIdx.x >> 6] = s;
    __syncthreads();
    if (threadIdx.x == 0)
        out[0] = 0.5f * (wsum[0] + wsum[1] + wsum[2] + wsum[3]) / (float)(B_ * T_);
}

// ---------------------------------------------------------------------------
extern "C" void kernel_launch(void* const* d_in, const int* in_sizes, int n_in,
                              void* d_out, int out_size, void* d_ws, size_t ws_size,
                              hipStream_t stream) {
    const float* x       = (const float*)d_in[0];   // [B,T,D]
    const float* W       = (const float*)d_in[1];   // [N,D]
    const float* bvec    = (const float*)d_in[2];   // [N]
    const int*   labels  = (const int*)d_in[3];     // [B,T]
    const int*   sampled = (const int*)d_in[4];     // [B,S]
    float* out = (float*)d_out;

    float* true_logit   = (float*)d_ws;                 // B*T floats
    float* denom        = true_logit + B_ * T_;         // B*T floats
    unsigned char* xf8  = (unsigned char*)(denom + B_ * T_);  // B*T*D fp8 (16.8 MB)
    unsigned char* Wf8  = xf8 + (size_t)B_ * T_ * D_;   // N*D fp8 (51.2 MB)

    const size_t NEED = (size_t)2 * B_ * T_ * 4
                      + (size_t)B_ * T_ * D_
                      + (size_t)N_ * D_;               // ~68.2 MB

    if (ws_size >= NEED) {
        prep_kernel<<<N_ * D_ / 2048 + B_ * T_ / 4, 256, 0, stream>>>(
            x, W, bvec, labels, true_logit, denom, xf8, Wf8);
        sampled_gemm_fp8<<<B_ * (T_ / BM) * (S_ / BN), 256, 0, stream>>>(
            xf8, Wf8, bvec, labels, sampled, denom);
    } else {
        true_logit_kernel<<<B_ * T_ / 4, 256, 0, stream>>>(
            x, W, bvec, labels, true_logit, denom);
        sampled_gemm<<<B_ * (T_ / BM) * (S_ / BN), 256, 0, stream>>>(
            x, W, bvec, labels, sampled, denom);
    }
    finalize_kernel<<<1, 256, 0, stream>>>(true_logit, denom, out);
}

// Round 3
// 1453.879 us; speedup vs baseline: 1.0010x; 1.0010x over previous
//
#include <hip/hip_runtime.h>
#include <hip/hip_bf16.h>
#include <math.h>
#include <stdint.h>

// Problem constants (from setup_inputs)
#define B_ 32
#define T_ 512
#define D_ 1024
#define N_ 50000
#define S_ 4096

// 1 / log(N+1) = 1 / log(50001)
#define INV_LOG_NP1 0.09242317f

// W is pre-scaled by 64 when converting to fp8 e4m3 (raw W*0.02 lands in the
// subnormal zone); the GEMM accumulator is multiplied by 1/64 in the epilogue.
#define WSCALE 64.0f
#define INV_WSCALE 0.015625f
#define LOG2E 1.4426950408889634f

// e8m0 scale = 127 -> 2^0 = 1.0 in every byte (opsel-proof)
#define SCALE_ONE 0x7F7F7F7F

typedef __attribute__((ext_vector_type(8))) short bf16x8;   // bf16 MFMA A/B frag
typedef __attribute__((ext_vector_type(4))) float f32x4;    // MFMA C/D frag
typedef __attribute__((ext_vector_type(4))) short s16x4;    // 8B store
typedef __attribute__((ext_vector_type(4))) int i32x4;      // half MX frag (16B)
typedef __attribute__((ext_vector_type(8))) int i32x8;      // MX MFMA A/B frag (32B)

// fp32 -> bf16 round-to-nearest-even (fallback path)
__device__ __forceinline__ short f2bf(float f) {
    unsigned u = __float_as_uint(f);
    u += 0x7fffu + ((u >> 16) & 1u);
    return (short)(u >> 16);
}

// pack 4 floats -> 4 fp8 e4m3 bytes (HW cvt, OCP format on gfx950)
__device__ __forceinline__ int pack_fp8x4(float a, float b, float c, float d) {
    int v = __builtin_amdgcn_cvt_pk_fp8_f32(a, b, 0, false);   // bytes 0,1
    v = __builtin_amdgcn_cvt_pk_fp8_f32(c, d, v, true);        // bytes 2,3
    return v;
}

// log E[count] for log-uniform unique sampling (TF formula), fp32 like the ref
__device__ __forceinline__ float log_expected(int id) {
    float p  = log1pf(1.0f / ((float)id + 1.0f)) * INV_LOG_NP1;  // P(c)
    return logf(-expm1f((float)S_ * log1pf(-p)));                // log(1-(1-p)^S)
}

// async global->LDS, 16 B per lane; LDS dest = wave-uniform base + lane*16
__device__ __forceinline__ void gload_lds16(const void* g, void* l) {
    __builtin_amdgcn_global_load_lds(
        (const __attribute__((address_space(1))) void*)g,
        (__attribute__((address_space(3))) void*)l, 16, 0, 0);
}

// Register-only concat of two 16-B halves into one 32-B MX fragment.
// NO address-taking (round-2 post-mortem: (int4*)&frag stores defeated SROA
// and put every fragment in scratch -> 1.4 GB spill writes/dispatch).
__device__ __forceinline__ i32x8 cat16(i32x4 lo, i32x4 hi) {
    return __builtin_shufflevector(lo, hi, 0, 1, 2, 3, 4, 5, 6, 7);
}

// ---------------------------------------------------------------------------
// Kernel P (fast path): fused {W fp32 -> fp8 table} + {true logits + x -> fp8}.
// Blocks [0, NCVT) convert W (each thread 8 elems, exactly covers N*D).
// Blocks [NCVT, NCVT + B*T/4) compute true logits, one wave per token, and
// emit x in fp8 (x is being read here anyway).
__global__ __launch_bounds__(256) void prep_kernel(
    const float* __restrict__ x, const float* __restrict__ W,
    const float* __restrict__ bvec, const int* __restrict__ labels,
    float* __restrict__ true_logit, float* __restrict__ denom,
    unsigned char* __restrict__ xf8, unsigned char* __restrict__ Wf8)
{
    constexpr int NCVT = N_ * D_ / 2048;        // 25000
    if (blockIdx.x < NCVT) {
        size_t i = ((size_t)blockIdx.x * 2048) + (size_t)threadIdx.x * 8;
        float4 a = *(const float4*)(W + i);
        float4 b = *(const float4*)(W + i + 4);
        int2 o;
        o.x = pack_fp8x4(a.x * WSCALE, a.y * WSCALE, a.z * WSCALE, a.w * WSCALE);
        o.y = pack_fp8x4(b.x * WSCALE, b.y * WSCALE, b.z * WSCALE, b.w * WSCALE);
        *(int2*)(Wf8 + i) = o;
        return;
    }
    int w = threadIdx.x >> 6, lane = threadIdx.x & 63;
    int token = (blockIdx.x - NCVT) * 4 + w;    // B*T/4 blocks, exact
    int lab = labels[token];
    const float4* xp = (const float4*)(x + (size_t)token * D_);
    const float4* wp = (const float4*)(W + (size_t)lab * D_);
    float acc = 0.0f;
#pragma unroll
    for (int j = 0; j < 4; ++j) {               // 1024 floats = 256 float4 / 64 lanes
        float4 a = xp[lane + 64 * j];
        float4 c = wp[lane + 64 * j];
        acc += a.x * c.x + a.y * c.y + a.z * c.z + a.w * c.w;
        int o = pack_fp8x4(a.x, a.y, a.z, a.w);
        *(int*)(xf8 + (size_t)token * D_ + (lane + 64 * j) * 4) = o;
    }
#pragma unroll
    for (int m = 32; m >= 1; m >>= 1) acc += __shfl_xor(acc, m);
    if (lane == 0) {
        float tl = acc + bvec[lab] - log_expected(lab);
        true_logit[token] = tl;
        denom[token] = __expf(tl);
    }
}

// ---------------------------------------------------------------------------
// Kernel 1 (FALLBACK): true logits only (no fp8 emit).
__global__ __launch_bounds__(256) void true_logit_kernel(
    const float* __restrict__ x, const float* __restrict__ W,
    const float* __restrict__ bvec, const int* __restrict__ labels,
    float* __restrict__ true_logit, float* __restrict__ denom)
{
    int w = threadIdx.x >> 6, lane = threadIdx.x & 63;
    int token = blockIdx.x * 4 + w;             // grid = B*T/4, exact
    int lab = labels[token];
    const float4* xp = (const float4*)(x + (size_t)token * D_);
    const float4* wp = (const float4*)(W + (size_t)lab * D_);
    float acc = 0.0f;
#pragma unroll
    for (int j = 0; j < 4; ++j) {
        float4 a = xp[lane + 64 * j];
        float4 c = wp[lane + 64 * j];
        acc += a.x * c.x + a.y * c.y + a.z * c.z + a.w * c.w;
    }
#pragma unroll
    for (int m = 32; m >= 1; m >>= 1) acc += __shfl_xor(acc, m);
    if (lane == 0) {
        float tl = acc + bvec[lab] - log_expected(lab);
        true_logit[token] = tl;
        denom[token] = __expf(tl);
    }
}

constexpr int BM = 128, BN = 128;

// ---------------------------------------------------------------------------
// Kernel 2 (FAST): fused sampled-logits GEMM + exp-sum epilogue, fp8 e4m3 via
// the block-scaled MX pipe (mfma_scale 16x16x128, unit e8m0 scales), single-
// buffered (m97-style) global_load_lds(16B) staging, BK=128 (bytes).
//
// K-PERMUTATION TRICK: result invariant under any K-permutation applied to
// both A and B.  Lane quad lq (=lane>>4) consumes global k = lq*32..lq*32+31:
// exactly the two staged 16-B chunks (2lq, 2lq+1) -> one K=128 MX fragment
// (32 B/lane), conflict-free ds_read_b128 x2.  A and B use the identical
// (lane,byte)->k mapping, so the HW's internal k ordering cannot break
// correctness.  Unit scales (0x7F) keep products bit-identical to the
// non-scaled fp8 path (verified rounds 1-2: absmax 0.0).
//
// LDS layout: row = 128 B = 8 chunks of 16 B; chunk c of row r at slot c^(r&7).
// Staging: lane l loads chunk (l&7)^(l>>3) of row seg*8+(l>>3).
//
// REGISTER DISCIPLINE (rounds 1+2 post-mortems):
//  - r1: all 8 frags live + int4 temporaries -> 256 VGPR + pressure spill.
//  - r2: (int4*)&frag construction -> SROA defeated -> frags in SCRATCH
//        (FETCH 2 GB / WRITE 1.4 GB of spill traffic, MfmaUtil 2.5%).
//  - now: B frags loaded once (32 VGPR) via shufflevector concat (pure
//        register op, no address-taking); A streamed one frag at a time.
//        Peak live ~155 < 170-reg cap of __launch_bounds__(256,3).
__global__ __launch_bounds__(256, 3) void sampled_gemm_fp8(
    const unsigned char* __restrict__ xf8, const unsigned char* __restrict__ Wf8,
    const float* __restrict__ bvec, const int* __restrict__ labels,
    const int* __restrict__ sampled, float* __restrict__ denom)
{
    constexpr int BK = 128;           // K-bytes (= K elems, fp8)
    __shared__ __align__(16) unsigned char At[BM * BK];   // 16 KB
    __shared__ __align__(16) unsigned char Bt[BN * BK];   // 16 KB
    __shared__ float colbias[BN];     // (b - logE) * log2(e)
    __shared__ int   ids[BN];
    __shared__ int   labT[BM];

    int bidx = blockIdx.x;            // grid = B * (T/BM) * (S/BN) = 32*4*32
    int b    = bidx >> 7;
    int rem  = bidx & 127;
    int mT   = rem >> 5;
    int nT   = rem & 31;

    int tid  = threadIdx.x;
    int w    = tid >> 6, lane = tid & 63;

    // ---- staging geometry: 1 KB per issue = 8 rows x 128 B ----
    int r = lane >> 3;                       // 0..7 row within 8-row segment
    int s = lane & 7;                        // LDS slot (16 B units)
    int c = s ^ r;                           // global chunk this lane loads

    int tokBase = b * T_ + mT * BM;
    const unsigned char* gA[4];
    const unsigned char* gB[4];
    unsigned char* lA[4];
    unsigned char* lB[4];
#pragma unroll
    for (int j = 0; j < 4; ++j) {
        int seg = 4 * w + j;                 // wave w stages segments 4w..4w+3
        int row = seg * 8 + r;               // 0..127
        gA[j] = xf8 + (size_t)(tokBase + row) * D_ + c * 16;
        int id = sampled[b * S_ + nT * BN + row];
        gB[j] = Wf8 + (size_t)id * D_ + c * 16;
        lA[j] = At + seg * 1024;             // 1 KB per segment
        lB[j] = Bt + seg * 1024;
    }

#define STAGE()                                                      \
    do {                                                             \
        _Pragma("unroll")                                            \
        for (int j = 0; j < 4; ++j) { gload_lds16(gA[j], lA[j]); gA[j] += BK; } \
        _Pragma("unroll")                                            \
        for (int j = 0; j < 4; ++j) { gload_lds16(gB[j], lB[j]); gB[j] += BK; } \
    } while (0)

    // Issue first tile ASAP; prologue transcendentals overlap the loads.
    STAGE();

    // ---- prologue: epilogue metadata into LDS ----
    if (tid < BN) {
        int id = sampled[b * S_ + nT * BN + tid];
        ids[tid] = id;
        colbias[tid] = (bvec[id] - log_expected(id)) * LOG2E;
    } else {
        int i = tid - BN;
        labT[i] = labels[b * T_ + mT * BM + i];
    }

    f32x4 acc[4][4];
#pragma unroll
    for (int mi = 0; mi < 4; ++mi)
#pragma unroll
        for (int ni = 0; ni < 4; ++ni) acc[mi][ni] = (f32x4){0.f, 0.f, 0.f, 0.f};

    int waveM = w >> 1, waveN = w & 1;
    int lr = lane & 15, lq = lane >> 4;
    // Fragment row byte-bases and per-chunk swizzled offsets
    int aRow[4], bRow[4];
#pragma unroll
    for (int i = 0; i < 4; ++i) {
        aRow[i] = (waveM * 64 + i * 16 + lr) * BK;
        bRow[i] = (waveN * 64 + i * 16 + lr) * BK;
    }
    int offP[2];
#pragma unroll
    for (int tp = 0; tp < 2; ++tp)
        offP[tp] = ((2 * lq + tp) ^ (lr & 7)) * 16;

    for (int k0 = 0; k0 < D_; k0 += BK) {
        if (k0) {
            __syncthreads();                  // LDS consumers of prev tile done
            STAGE();
        }
        __syncthreads();                      // drain staging (vmcnt(0))

        // B fragments: loaded once, reused by all 4 A fragments (32 VGPR).
        i32x8 bv[4];
#pragma unroll
        for (int ni = 0; ni < 4; ++ni)
            bv[ni] = cat16(*(const i32x4*)(Bt + bRow[ni] + offP[0]),
                           *(const i32x4*)(Bt + bRow[ni] + offP[1]));
        // A fragments streamed one at a time (8 VGPR live).
#pragma unroll
        for (int mi = 0; mi < 4; ++mi) {
            i32x8 a = cat16(*(const i32x4*)(At + aRow[mi] + offP[0]),
                            *(const i32x4*)(At + aRow[mi] + offP[1]));
#pragma unroll
            for (int ni = 0; ni < 4; ++ni)
                acc[mi][ni] = __builtin_amdgcn_mfma_scale_f32_16x16x128_f8f6f4(
                    a, bv[ni], acc[mi][ni],
                    0, 0,                      // cbsz/blgp: fp8 e4m3 both
                    0, SCALE_ONE,              // opsel_a, scale_a = 1.0
                    0, SCALE_ONE);             // opsel_b, scale_b = 1.0
        }
    }
#undef STAGE

    // Epilogue: exp2-domain (acc and bias pre-scaled by log2e), accidental-hit
    // mask, row-sum, atomicAdd.
    // C/D layout (shape-determined, verified m89/m91/m127):
    // col = lane&15, row = (lane>>4)*4 + reg
    const float accScale = INV_WSCALE * LOG2E;
    float* dptr = denom + b * T_ + mT * BM;
#pragma unroll
    for (int mi = 0; mi < 4; ++mi) {
#pragma unroll
        for (int rr = 0; rr < 4; ++rr) {
            int localRow = waveM * 64 + mi * 16 + lq * 4 + rr;
            int lab = labT[localRow];
            float sum = 0.0f;
#pragma unroll
            for (int ni = 0; ni < 4; ++ni) {
                int col = waveN * 64 + ni * 16 + lr;
                float v = acc[mi][ni][rr] * accScale + colbias[col];
                sum += (ids[col] == lab) ? 0.0f : exp2f(v);
            }
            sum += __shfl_xor(sum, 1);
            sum += __shfl_xor(sum, 2);
            sum += __shfl_xor(sum, 4);
            sum += __shfl_xor(sum, 8);
            if (lr == 0) atomicAdd(&dptr[localRow], sum);
        }
    }
}

// ---------------------------------------------------------------------------
// Kernel 2 (FALLBACK): register-staging fp32->bf16 GEMM (small-ws path).
__global__ __launch_bounds__(256) void sampled_gemm(
    const float* __restrict__ x, const float* __restrict__ W,
    const float* __restrict__ bvec, const int* __restrict__ labels,
    const int* __restrict__ sampled, float* __restrict__ denom)
{
    constexpr int FBK = 32;
    __shared__ short At[BM * FBK];
    __shared__ short Bt[BN * FBK];
    __shared__ float colbias[BN];
    __shared__ int   ids[BN];
    __shared__ int   labT[BM];

    int bidx = blockIdx.x;
    int b    = bidx >> 7;
    int rem  = bidx & 127;
    int mT   = rem >> 5;
    int nT   = rem & 31;
    int tid = threadIdx.x;

    if (tid < BN) {
        int id = sampled[b * S_ + nT * BN + tid];
        ids[tid] = id;
        colbias[tid] = bvec[id] - log_expected(id);
    } else {
        int i = tid - BN;
        labT[i] = labels[b * T_ + mT * BM + i];
    }
    __syncthreads();

    const float* asrc[4];
    const float* bsrc[4];
    int ch = tid & 7;
#pragma unroll
    for (int j = 0; j < 4; ++j) {
        int row = (tid >> 3) + 32 * j;
        asrc[j] = x + ((size_t)(b * T_ + mT * BM + row)) * D_ + ch * 4;
        bsrc[j] = W + (size_t)ids[row] * D_ + ch * 4;
    }

    f32x4 acc[4][4];
#pragma unroll
    for (int mi = 0; mi < 4; ++mi)
#pragma unroll
        for (int ni = 0; ni < 4; ++ni) acc[mi][ni] = (f32x4){0.f, 0.f, 0.f, 0.f};

    int w = tid >> 6, lane = tid & 63;
    int waveM = w >> 1, waveN = w & 1;
    int lr = lane & 15, lq = lane >> 4;

    for (int k0 = 0; k0 < D_; k0 += FBK) {
        __syncthreads();
#pragma unroll
        for (int j = 0; j < 4; ++j) {
            int row = (tid >> 3) + 32 * j;
            float4 va = *(const float4*)(asrc[j] + k0);
            s16x4 pa = {f2bf(va.x), f2bf(va.y), f2bf(va.z), f2bf(va.w)};
            *(s16x4*)&At[row * FBK + ch * 4] = pa;
            float4 vb = *(const float4*)(bsrc[j] + k0);
            s16x4 pb = {f2bf(vb.x), f2bf(vb.y), f2bf(vb.z), f2bf(vb.w)};
            *(s16x4*)&Bt[row * FBK + ch * 4] = pb;
        }
        __syncthreads();
        bf16x8 af[4], bfr[4];
#pragma unroll
        for (int mi = 0; mi < 4; ++mi)
            af[mi] = *(const bf16x8*)&At[(waveM * 64 + mi * 16 + lr) * FBK + lq * 8];
#pragma unroll
        for (int ni = 0; ni < 4; ++ni)
            bfr[ni] = *(const bf16x8*)&Bt[(waveN * 64 + ni * 16 + lr) * FBK + lq * 8];
#pragma unroll
        for (int mi = 0; mi < 4; ++mi)
#pragma unroll
            for (int ni = 0; ni < 4; ++ni)
                acc[mi][ni] = __builtin_amdgcn_mfma_f32_16x16x32_bf16(
                    af[mi], bfr[ni], acc[mi][ni], 0, 0, 0);
    }

    float* dptr = denom + b * T_ + mT * BM;
#pragma unroll
    for (int mi = 0; mi < 4; ++mi) {
#pragma unroll
        for (int rr = 0; rr < 4; ++rr) {
            int localRow = waveM * 64 + mi * 16 + lq * 4 + rr;
            int lab = labT[localRow];
            float sum = 0.0f;
#pragma unroll
            for (int ni = 0; ni < 4; ++ni) {
                int col = waveN * 64 + ni * 16 + lr;
                float v = acc[mi][ni][rr] + colbias[col];
                sum += (ids[col] == lab) ? 0.0f : __expf(v);
            }
            sum += __shfl_xor(sum, 1);
            sum += __shfl_xor(sum, 2);
            sum += __shfl_xor(sum, 4);
            sum += __shfl_xor(sum, 8);
            if (lr == 0) atomicAdd(&dptr[localRow], sum);
        }
    }
}

// ---------------------------------------------------------------------------
// Kernel 3: token_loss = log(denom) - true_logit; out = 0.5 * mean
__global__ __launch_bounds__(256) void finalize_kernel(
    const float* __restrict__ true_logit, const float* __restrict__ denom,
    float* __restrict__ out)
{
    float s = 0.0f;
    for (int i = threadIdx.x; i < B_ * T_; i += 256)
        s += __logf(denom[i]) - true_logit[i];
#pragma unroll
    for (int m = 32; m >= 1; m >>= 1) s += __shfl_xor(s, m);
    __shared__ float wsum[4];
    if ((threadIdx.x & 63) == 0) wsum[threadIdx.x >> 6] = s;
    __syncthreads();
    if (threadIdx.x == 0)
        out[0] = 0.5f * (wsum[0] + wsum[1] + wsum[2] + wsum[3]) / (float)(B_ * T_);
}

// ---------------------------------------------------------------------------
extern "C" void kernel_launch(void* const* d_in, const int* in_sizes, int n_in,
                              void* d_out, int out_size, void* d_ws, size_t ws_size,
                              hipStream_t stream) {
    const float* x       = (const float*)d_in[0];   // [B,T,D]
    const float* W       = (const float*)d_in[1];   // [N,D]
    const float* bvec    = (const float*)d_in[2];   // [N]
    const int*   labels  = (const int*)d_in[3];     // [B,T]
    const int*   sampled = (const int*)d_in[4];     // [B,S]
    float* out = (float*)d_out;

    float* true_logit   = (float*)d_ws;                 // B*T floats
    float* denom        = true_logit + B_ * T_;         // B*T floats
    unsigned char* xf8  = (unsigned char*)(denom + B_ * T_);  // B*T*D fp8 (16.8 MB)
    unsigned char* Wf8  = xf8 + (size_t)B_ * T_ * D_;   // N*D fp8 (51.2 MB)

    const size_t NEED = (size_t)2 * B_ * T_ * 4
                      + (size_t)B_ * T_ * D_
                      + (size_t)N_ * D_;               // ~68.2 MB

    if (ws_size >= NEED) {
        prep_kernel<<<N_ * D_ / 2048 + B_ * T_ / 4, 256, 0, stream>>>(
            x, W, bvec, labels, true_logit, denom, xf8, Wf8);
        sampled_gemm_fp8<<<B_ * (T_ / BM) * (S_ / BN), 256, 0, stream>>>(
            xf8, Wf8, bvec, labels, sampled, denom);
    } else {
        true_logit_kernel<<<B_ * T_ / 4, 256, 0, stream>>>(
            x, W, bvec, labels, true_logit, denom);
        sampled_gemm<<<B_ * (T_ / BM) * (S_ / BN), 256, 0, stream>>>(
            x, W, bvec, labels, sampled, denom);
    }
    finalize_kernel<<<1, 256, 0, stream>>>(true_logit, denom, out);
}

// Round 4
// 485.225 us; speedup vs baseline: 2.9992x; 2.9963x over previous
//
#include <hip/hip_runtime.h>
#include <hip/hip_bf16.h>
#include <math.h>
#include <stdint.h>

// Problem constants (from setup_inputs)
#define B_ 32
#define T_ 512
#define D_ 1024
#define N_ 50000
#define S_ 4096

// 1 / log(N+1) = 1 / log(50001)
#define INV_LOG_NP1 0.09242317f

// W is pre-scaled by 64 when converting to fp8 e4m3 (raw W*0.02 lands in the
// subnormal zone); the GEMM accumulator is multiplied by 1/64 in the epilogue.
#define WSCALE 64.0f
#define INV_WSCALE 0.015625f
#define LOG2E 1.4426950408889634f

typedef __attribute__((ext_vector_type(8))) short bf16x8;   // bf16 MFMA A/B frag
typedef __attribute__((ext_vector_type(4))) float f32x4;    // MFMA C/D frag
typedef __attribute__((ext_vector_type(4))) short s16x4;    // 8B store

// fp32 -> bf16 round-to-nearest-even (fallback path)
__device__ __forceinline__ short f2bf(float f) {
    unsigned u = __float_as_uint(f);
    u += 0x7fffu + ((u >> 16) & 1u);
    return (short)(u >> 16);
}

// pack 4 floats -> 4 fp8 e4m3 bytes (HW cvt, OCP format on gfx950)
__device__ __forceinline__ int pack_fp8x4(float a, float b, float c, float d) {
    int v = __builtin_amdgcn_cvt_pk_fp8_f32(a, b, 0, false);   // bytes 0,1
    v = __builtin_amdgcn_cvt_pk_fp8_f32(c, d, v, true);        // bytes 2,3
    return v;
}

// log E[count] for log-uniform unique sampling (TF formula), fp32 like the ref
__device__ __forceinline__ float log_expected(int id) {
    float p  = log1pf(1.0f / ((float)id + 1.0f)) * INV_LOG_NP1;  // P(c)
    return logf(-expm1f((float)S_ * log1pf(-p)));                // log(1-(1-p)^S)
}

// async global->LDS, 16 B per lane; LDS dest = wave-uniform base + lane*16
__device__ __forceinline__ void gload_lds16(const void* g, void* l) {
    __builtin_amdgcn_global_load_lds(
        (const __attribute__((address_space(1))) void*)g,
        (__attribute__((address_space(3))) void*)l, 16, 0, 0);
}

// ---------------------------------------------------------------------------
// Kernel P (fast path): fused {W fp32 -> fp8 table} + {true logits + x -> fp8}.
// Blocks [0, NCVT) convert W (each thread 8 elems, exactly covers N*D).
// Blocks [NCVT, NCVT + B*T/4) compute true logits, one wave per token, and
// emit x in fp8 (x is being read here anyway).  Fusion measured neutral vs
// split (r0 vs r1 non-GEMM remainder: 340 vs 342 us) — kept for one fewer
// launch.
__global__ __launch_bounds__(256) void prep_kernel(
    const float* __restrict__ x, const float* __restrict__ W,
    const float* __restrict__ bvec, const int* __restrict__ labels,
    float* __restrict__ true_logit, float* __restrict__ denom,
    unsigned char* __restrict__ xf8, unsigned char* __restrict__ Wf8)
{
    constexpr int NCVT = N_ * D_ / 2048;        // 25000
    if (blockIdx.x < NCVT) {
        size_t i = ((size_t)blockIdx.x * 2048) + (size_t)threadIdx.x * 8;
        float4 a = *(const float4*)(W + i);
        float4 b = *(const float4*)(W + i + 4);
        int2 o;
        o.x = pack_fp8x4(a.x * WSCALE, a.y * WSCALE, a.z * WSCALE, a.w * WSCALE);
        o.y = pack_fp8x4(b.x * WSCALE, b.y * WSCALE, b.z * WSCALE, b.w * WSCALE);
        *(int2*)(Wf8 + i) = o;
        return;
    }
    int w = threadIdx.x >> 6, lane = threadIdx.x & 63;
    int token = (blockIdx.x - NCVT) * 4 + w;    // B*T/4 blocks, exact
    int lab = labels[token];
    const float4* xp = (const float4*)(x + (size_t)token * D_);
    const float4* wp = (const float4*)(W + (size_t)lab * D_);
    float acc = 0.0f;
#pragma unroll
    for (int j = 0; j < 4; ++j) {               // 1024 floats = 256 float4 / 64 lanes
        float4 a = xp[lane + 64 * j];
        float4 c = wp[lane + 64 * j];
        acc += a.x * c.x + a.y * c.y + a.z * c.z + a.w * c.w;
        int o = pack_fp8x4(a.x, a.y, a.z, a.w);
        *(int*)(xf8 + (size_t)token * D_ + (lane + 64 * j) * 4) = o;
    }
#pragma unroll
    for (int m = 32; m >= 1; m >>= 1) acc += __shfl_xor(acc, m);
    if (lane == 0) {
        float tl = acc + bvec[lab] - log_expected(lab);
        true_logit[token] = tl;
        denom[token] = __expf(tl);
    }
}

// ---------------------------------------------------------------------------
// Kernel 1 (FALLBACK): true logits only (no fp8 emit).
__global__ __launch_bounds__(256) void true_logit_kernel(
    const float* __restrict__ x, const float* __restrict__ W,
    const float* __restrict__ bvec, const int* __restrict__ labels,
    float* __restrict__ true_logit, float* __restrict__ denom)
{
    int w = threadIdx.x >> 6, lane = threadIdx.x & 63;
    int token = blockIdx.x * 4 + w;             // grid = B*T/4, exact
    int lab = labels[token];
    const float4* xp = (const float4*)(x + (size_t)token * D_);
    const float4* wp = (const float4*)(W + (size_t)lab * D_);
    float acc = 0.0f;
#pragma unroll
    for (int j = 0; j < 4; ++j) {
        float4 a = xp[lane + 64 * j];
        float4 c = wp[lane + 64 * j];
        acc += a.x * c.x + a.y * c.y + a.z * c.z + a.w * c.w;
    }
#pragma unroll
    for (int m = 32; m >= 1; m >>= 1) acc += __shfl_xor(acc, m);
    if (lane == 0) {
        float tl = acc + bvec[lab] - log_expected(lab);
        true_logit[token] = tl;
        denom[token] = __expf(tl);
    }
}

constexpr int BM = 128, BN = 128;

// ---------------------------------------------------------------------------
// Kernel 2 (FAST): fused sampled-logits GEMM + exp-sum epilogue, fp8 e4m3,
// single-buffered (m97-style) global_load_lds(16B) staging, BK=128 (bytes).
// *** ROUND-0 VERIFIED FORM: non-scaled mfma_f32_16x16x32_fp8_fp8, acc in
// AGPRs, 76 VGPR, ~941 TF. ***  The MX (mfma_scale 16x16x128) variant was
// abandoned after rounds 1-3: through HIP builtins its operands/acc refuse
// AGPR allocation, so any register cap spills the accumulator to scratch
// (r2/r3: 1.4 GB spill writes/dispatch, MfmaUtil 2.5%) and uncapped it pins
// 256 VGPR at 1 block/CU (r1).  Do not retry without evidence the compiler
// can AGPR-allocate mfma_scale accumulators.
//
// K-PERMUTATION TRICK: the GEMM result is invariant under any permutation of
// the K index applied to both A and B.  We relabel so that MFMA kstep t, lane
// quad lq (=lane>>4) consumes global k = lq*32 + t*8..+7.  Then a lane's data
// for a kstep-PAIR tp (t=2tp,2tp+1) is 16 contiguous global bytes = exactly
// one staged 16-B chunk (index 2lq+tp) -> conflict-free ds_read_b128:
// 8-lane phases read slots (2lq+tp)^(lr&7) = 8 distinct slots x 4 banks = all
// 32 banks.  Halves ds_read instruction count vs b64-per-kstep.
//
// LDS layout: row = 128 B = 8 chunks of 16 B; chunk c of row r at slot
// c^(r&7).  Staging: lane l loads chunk (l&7)^(l>>3) of row seg*8+(l>>3).
//
// K-loop: 8 iters of { [sync; STAGE;] sync; 2 pair-steps x (2x16) mfma }.
__global__ __launch_bounds__(256) void sampled_gemm_fp8(
    const unsigned char* __restrict__ xf8, const unsigned char* __restrict__ Wf8,
    const float* __restrict__ bvec, const int* __restrict__ labels,
    const int* __restrict__ sampled, float* __restrict__ denom)
{
    constexpr int BK = 128;           // K-bytes (= K elems, fp8)
    __shared__ __align__(16) unsigned char At[BM * BK];   // 16 KB
    __shared__ __align__(16) unsigned char Bt[BN * BK];   // 16 KB
    __shared__ float colbias[BN];     // (b - logE) * log2(e)
    __shared__ int   ids[BN];
    __shared__ int   labT[BM];

    int bidx = blockIdx.x;            // grid = B * (T/BM) * (S/BN) = 32*4*32
    int b    = bidx >> 7;
    int rem  = bidx & 127;
    int mT   = rem >> 5;
    int nT   = rem & 31;

    int tid  = threadIdx.x;
    int w    = tid >> 6, lane = tid & 63;

    // ---- staging geometry: 1 KB per issue = 8 rows x 128 B ----
    int r = lane >> 3;                       // 0..7 row within 8-row segment
    int s = lane & 7;                        // LDS slot (16 B units)
    int c = s ^ r;                           // global chunk this lane loads

    int tokBase = b * T_ + mT * BM;
    const unsigned char* gA[4];
    const unsigned char* gB[4];
    unsigned char* lA[4];
    unsigned char* lB[4];
#pragma unroll
    for (int j = 0; j < 4; ++j) {
        int seg = 4 * w + j;                 // wave w stages segments 4w..4w+3
        int row = seg * 8 + r;               // 0..127
        gA[j] = xf8 + (size_t)(tokBase + row) * D_ + c * 16;
        int id = sampled[b * S_ + nT * BN + row];
        gB[j] = Wf8 + (size_t)id * D_ + c * 16;
        lA[j] = At + seg * 1024;             // 1 KB per segment
        lB[j] = Bt + seg * 1024;
    }

#define STAGE()                                                      \
    do {                                                             \
        _Pragma("unroll")                                            \
        for (int j = 0; j < 4; ++j) { gload_lds16(gA[j], lA[j]); gA[j] += BK; } \
        _Pragma("unroll")                                            \
        for (int j = 0; j < 4; ++j) { gload_lds16(gB[j], lB[j]); gB[j] += BK; } \
    } while (0)

    // Issue first tile ASAP; prologue transcendentals overlap the loads.
    STAGE();

    // ---- prologue: epilogue metadata into LDS ----
    if (tid < BN) {
        int id = sampled[b * S_ + nT * BN + tid];
        ids[tid] = id;
        colbias[tid] = (bvec[id] - log_expected(id)) * LOG2E;
    } else {
        int i = tid - BN;
        labT[i] = labels[b * T_ + mT * BM + i];
    }

    f32x4 acc[4][4];
#pragma unroll
    for (int mi = 0; mi < 4; ++mi)
#pragma unroll
        for (int ni = 0; ni < 4; ++ni) acc[mi][ni] = (f32x4){0.f, 0.f, 0.f, 0.f};

    int waveM = w >> 1, waveN = w & 1;
    int lr = lane & 15, lq = lane >> 4;
    // Fragment row byte-bases and per-pair swizzled chunk offsets
    int aRow[4], bRow[4];
#pragma unroll
    for (int i = 0; i < 4; ++i) {
        aRow[i] = (waveM * 64 + i * 16 + lr) * BK;
        bRow[i] = (waveN * 64 + i * 16 + lr) * BK;
    }
    int offP[2];
#pragma unroll
    for (int tp = 0; tp < 2; ++tp)
        offP[tp] = ((2 * lq + tp) ^ (lr & 7)) * 16;

    for (int k0 = 0; k0 < D_; k0 += BK) {
        if (k0) {
            __syncthreads();                  // LDS consumers of prev tile done
            STAGE();
        }
        __syncthreads();                      // drain staging (vmcnt(0))
#pragma unroll
        for (int tp = 0; tp < 2; ++tp) {      // two kstep-pairs per BK=128 tile
            long2 av[4], bv[4];
#pragma unroll
            for (int mi = 0; mi < 4; ++mi)
                av[mi] = *(const long2*)(At + aRow[mi] + offP[tp]);
#pragma unroll
            for (int ni = 0; ni < 4; ++ni)
                bv[ni] = *(const long2*)(Bt + bRow[ni] + offP[tp]);
#pragma unroll
            for (int mi = 0; mi < 4; ++mi)
#pragma unroll
                for (int ni = 0; ni < 4; ++ni)
                    acc[mi][ni] = __builtin_amdgcn_mfma_f32_16x16x32_fp8_fp8(
                        av[mi].x, bv[ni].x, acc[mi][ni], 0, 0, 0);
#pragma unroll
            for (int mi = 0; mi < 4; ++mi)
#pragma unroll
                for (int ni = 0; ni < 4; ++ni)
                    acc[mi][ni] = __builtin_amdgcn_mfma_f32_16x16x32_fp8_fp8(
                        av[mi].y, bv[ni].y, acc[mi][ni], 0, 0, 0);
        }
    }
#undef STAGE

    // Epilogue: exp2-domain (acc and bias pre-scaled by log2e), accidental-hit
    // mask, row-sum, atomicAdd.
    // C/D layout (verified m89/m91): col = lane&15, row = (lane>>4)*4 + reg
    const float accScale = INV_WSCALE * LOG2E;
    float* dptr = denom + b * T_ + mT * BM;
#pragma unroll
    for (int mi = 0; mi < 4; ++mi) {
#pragma unroll
        for (int rr = 0; rr < 4; ++rr) {
            int localRow = waveM * 64 + mi * 16 + lq * 4 + rr;
            int lab = labT[localRow];
            float sum = 0.0f;
#pragma unroll
            for (int ni = 0; ni < 4; ++ni) {
                int col = waveN * 64 + ni * 16 + lr;
                float v = acc[mi][ni][rr] * accScale + colbias[col];
                sum += (ids[col] == lab) ? 0.0f : exp2f(v);
            }
            sum += __shfl_xor(sum, 1);
            sum += __shfl_xor(sum, 2);
            sum += __shfl_xor(sum, 4);
            sum += __shfl_xor(sum, 8);
            if (lr == 0) atomicAdd(&dptr[localRow], sum);
        }
    }
}

// ---------------------------------------------------------------------------
// Kernel 2 (FALLBACK): register-staging fp32->bf16 GEMM (small-ws path).
__global__ __launch_bounds__(256) void sampled_gemm(
    const float* __restrict__ x, const float* __restrict__ W,
    const float* __restrict__ bvec, const int* __restrict__ labels,
    const int* __restrict__ sampled, float* __restrict__ denom)
{
    constexpr int FBK = 32;
    __shared__ short At[BM * FBK];
    __shared__ short Bt[BN * FBK];
    __shared__ float colbias[BN];
    __shared__ int   ids[BN];
    __shared__ int   labT[BM];

    int bidx = blockIdx.x;
    int b    = bidx >> 7;
    int rem  = bidx & 127;
    int mT   = rem >> 5;
    int nT   = rem & 31;
    int tid = threadIdx.x;

    if (tid < BN) {
        int id = sampled[b * S_ + nT * BN + tid];
        ids[tid] = id;
        colbias[tid] = bvec[id] - log_expected(id);
    } else {
        int i = tid - BN;
        labT[i] = labels[b * T_ + mT * BM + i];
    }
    __syncthreads();

    const float* asrc[4];
    const float* bsrc[4];
    int ch = tid & 7;
#pragma unroll
    for (int j = 0; j < 4; ++j) {
        int row = (tid >> 3) + 32 * j;
        asrc[j] = x + ((size_t)(b * T_ + mT * BM + row)) * D_ + ch * 4;
        bsrc[j] = W + (size_t)ids[row] * D_ + ch * 4;
    }

    f32x4 acc[4][4];
#pragma unroll
    for (int mi = 0; mi < 4; ++mi)
#pragma unroll
        for (int ni = 0; ni < 4; ++ni) acc[mi][ni] = (f32x4){0.f, 0.f, 0.f, 0.f};

    int w = tid >> 6, lane = tid & 63;
    int waveM = w >> 1, waveN = w & 1;
    int lr = lane & 15, lq = lane >> 4;

    for (int k0 = 0; k0 < D_; k0 += FBK) {
        __syncthreads();
#pragma unroll
        for (int j = 0; j < 4; ++j) {
            int row = (tid >> 3) + 32 * j;
            float4 va = *(const float4*)(asrc[j] + k0);
            s16x4 pa = {f2bf(va.x), f2bf(va.y), f2bf(va.z), f2bf(va.w)};
            *(s16x4*)&At[row * FBK + ch * 4] = pa;
            float4 vb = *(const float4*)(bsrc[j] + k0);
            s16x4 pb = {f2bf(vb.x), f2bf(vb.y), f2bf(vb.z), f2bf(vb.w)};
            *(s16x4*)&Bt[row * FBK + ch * 4] = pb;
        }
        __syncthreads();
        bf16x8 af[4], bfr[4];
#pragma unroll
        for (int mi = 0; mi < 4; ++mi)
            af[mi] = *(const bf16x8*)&At[(waveM * 64 + mi * 16 + lr) * FBK + lq * 8];
#pragma unroll
        for (int ni = 0; ni < 4; ++ni)
            bfr[ni] = *(const bf16x8*)&Bt[(waveN * 64 + ni * 16 + lr) * FBK + lq * 8];
#pragma unroll
        for (int mi = 0; mi < 4; ++mi)
#pragma unroll
            for (int ni = 0; ni < 4; ++ni)
                acc[mi][ni] = __builtin_amdgcn_mfma_f32_16x16x32_bf16(
                    af[mi], bfr[ni], acc[mi][ni], 0, 0, 0);
    }

    float* dptr = denom + b * T_ + mT * BM;
#pragma unroll
    for (int mi = 0; mi < 4; ++mi) {
#pragma unroll
        for (int rr = 0; rr < 4; ++rr) {
            int localRow = waveM * 64 + mi * 16 + lq * 4 + rr;
            int lab = labT[localRow];
            float sum = 0.0f;
#pragma unroll
            for (int ni = 0; ni < 4; ++ni) {
                int col = waveN * 64 + ni * 16 + lr;
                float v = acc[mi][ni][rr] + colbias[col];
                sum += (ids[col] == lab) ? 0.0f : __expf(v);
            }
            sum += __shfl_xor(sum, 1);
            sum += __shfl_xor(sum, 2);
            sum += __shfl_xor(sum, 4);
            sum += __shfl_xor(sum, 8);
            if (lr == 0) atomicAdd(&dptr[localRow], sum);
        }
    }
}

// ---------------------------------------------------------------------------
// Kernel 3: token_loss = log(denom) - true_logit; out = 0.5 * mean
__global__ __launch_bounds__(256) void finalize_kernel(
    const float* __restrict__ true_logit, const float* __restrict__ denom,
    float* __restrict__ out)
{
    float s = 0.0f;
    for (int i = threadIdx.x; i < B_ * T_; i += 256)
        s += __logf(denom[i]) - true_logit[i];
#pragma unroll
    for (int m = 32; m >= 1; m >>= 1) s += __shfl_xor(s, m);
    __shared__ float wsum[4];
    if ((threadIdx.x & 63) == 0) wsum[threadIdx.x >> 6] = s;
    __syncthreads();
    if (threadIdx.x == 0)
        out[0] = 0.5f * (wsum[0] + wsum[1] + wsum[2] + wsum[3]) / (float)(B_ * T_);
}

// ---------------------------------------------------------------------------
extern "C" void kernel_launch(void* const* d_in, const int* in_sizes, int n_in,
                              void* d_out, int out_size, void* d_ws, size_t ws_size,
                              hipStream_t stream) {
    const float* x       = (const float*)d_in[0];   // [B,T,D]
    const float* W       = (const float*)d_in[1];   // [N,D]
    const float* bvec    = (const float*)d_in[2];   // [N]
    const int*   labels  = (const int*)d_in[3];     // [B,T]
    const int*   sampled = (const int*)d_in[4];     // [B,S]
    float* out = (float*)d_out;

    float* true_logit   = (float*)d_ws;                 // B*T floats
    float* denom        = true_logit + B_ * T_;         // B*T floats
    unsigned char* xf8  = (unsigned char*)(denom + B_ * T_);  // B*T*D fp8 (16.8 MB)
    unsigned char* Wf8  = xf8 + (size_t)B_ * T_ * D_;   // N*D fp8 (51.2 MB)

    const size_t NEED = (size_t)2 * B_ * T_ * 4
                      + (size_t)B_ * T_ * D_
                      + (size_t)N_ * D_;               // ~68.2 MB

    if (ws_size >= NEED) {
        prep_kernel<<<N_ * D_ / 2048 + B_ * T_ / 4, 256, 0, stream>>>(
            x, W, bvec, labels, true_logit, denom, xf8, Wf8);
        sampled_gemm_fp8<<<B_ * (T_ / BM) * (S_ / BN), 256, 0, stream>>>(
            xf8, Wf8, bvec, labels, sampled, denom);
    } else {
        true_logit_kernel<<<B_ * T_ / 4, 256, 0, stream>>>(
            x, W, bvec, labels, true_logit, denom);
        sampled_gemm<<<B_ * (T_ / BM) * (S_ / BN), 256, 0, stream>>>(
            x, W, bvec, labels, sampled, denom);
    }
    finalize_kernel<<<1, 256, 0, stream>>>(true_logit, denom, out);
}